// Round 15
// baseline (3781.243 us; speedup 1.0000x reference)
//
// R15 == R14 with __launch_bounds__(512, 1): min-blocks/CU=1 -> 2 waves/SIMD -> 256-VGPR budget
#include <hip/hip_runtime.h>
#include <hip/hip_bf16.h>
#include <cstdint>

#define BATCH 4096
#define DIM   512
#define HID   1024
#define TSTEPS 20
#define NBLK  128
#define NTHR  512

typedef unsigned short u16;
typedef short s16x8 __attribute__((ext_vector_type(8)));
typedef float f32x4 __attribute__((ext_vector_type(4)));

__device__ __forceinline__ u16 f2bf(float f) {
    unsigned int u = __float_as_uint(f);
    u = (u + 0x7FFFu + ((u >> 16) & 1u)) >> 16;   // RNE
    return (u16)u;
}

__device__ __forceinline__ float fast_tanh(float x) {
    float ax = __builtin_fabsf(x);
    float e  = __expf(2.0f * ax);                 // inf for large ax -> t = 1
    float t  = 1.0f - 2.0f * __builtin_amdgcn_rcpf(e + 1.0f);
    return __builtin_copysignf(t, x);
}

// out[0] = x0 ; ybf = bf16(x0)
__global__ void init_state(const float* __restrict__ x0, float* __restrict__ out0,
                           u16* __restrict__ ybf, int n) {
    int i = blockIdx.x * blockDim.x + threadIdx.x;
    if (i < n) { float v = x0[i]; out0[i] = v; ybf[i] = f2bf(v); }
}

// Pack W1 [512k][1024n] f32 -> W1P bf16 in MFMA B-frag order:
// u16 idx = (((w*16 + ks)*8 + cg)*64 + lane)*8 + e
__global__ void pack_w1(const float* __restrict__ W1, u16* __restrict__ W1P) {
    int pid = blockIdx.x * 256 + threadIdx.x;
    int e  = pid & 7;
    int l  = (pid >> 3) & 63;
    int cg = (pid >> 9) & 7;
    int ks = (pid >> 12) & 15;
    int w  = (pid >> 16) & 7;
    int n = w * 128 + cg * 16 + (l & 15);
    int k = ks * 32 + (l >> 4) * 8 + e;
    W1P[pid] = f2bf(W1[(size_t)k * HID + n]);
}

// Pack W2 [1024k][512n] f32 -> W2P bf16:
// u16 idx = (((w*32 + ks)*4 + cf)*64 + lane)*8 + e
__global__ void pack_w2(const float* __restrict__ W2, u16* __restrict__ W2P) {
    int pid = blockIdx.x * 256 + threadIdx.x;
    int e  = pid & 7;
    int l  = (pid >> 3) & 63;
    int cf = (pid >> 9) & 3;
    int ks = (pid >> 11) & 31;
    int w  = (pid >> 16) & 7;
    int n = w * 64 + cf * 16 + (l & 15);
    int k = ks * 32 + (l >> 4) * 8 + e;
    W2P[pid] = f2bf(W2[(size_t)k * DIM + n]);
}

// Fused RK4 stage: one launch computes k = f(y_arg) for all 4096 rows and
// applies the stage's epilogue. Block = 32-row strip, 512 threads.
// LDS frag-tile layout (16r x 32k tile contiguous 1KB; elem (r,k) at
// ((k>>3)&3)*128 + r*8 + (k&7)) -> all ds_read_b128 conflict-free.
__global__ __launch_bounds__(NTHR, 1) void ode_stage(
    const u16* __restrict__ ybf,          // y-arg bf16 [4096][512] (in-place updated)
    const float* __restrict__ b1, const float* __restrict__ b2,
    const u16* __restrict__ W1P, const u16* __restrict__ W2P,
    const float* __restrict__ ybase_g,    // trajectory slot s (f32)
    float* __restrict__ ynext_g,          // trajectory slot s+1 (f32)
    float* __restrict__ accum,            // f32 [4096][512] k-accumulator
    u16* __restrict__ ybf_next,           // == ybf (block-local in-place)
    const float* __restrict__ tgrid, int step, int st)
{
    __shared__ u16 hs[64 * 512];   // 64 KiB: h strip [32r][1024h], 64 frag-tiles
    __shared__ u16 ys[32 * 512];   // 32 KiB: y strip [32r][512k],  32 frag-tiles

    const int tid  = threadIdx.x;
    const int lane = tid & 63;
    const int w    = tid >> 6;            // wave 0..7
    const int row0 = blockIdx.x * 32;
    const int lr   = (lane >> 4) * 4;
    const int lc   = lane & 15;
    const int q    = lane >> 4;

    // ---- load y strip (bf16 global, coalesced) -> ys frag-tiles ----
#pragma unroll
    for (int t_ = 0; t_ < 4; ++t_) {
        int c  = tid + t_ * NTHR;             // 16B chunk id, 0..2047
        int r  = c >> 6;                      // 0..31
        int k0 = (c & 63) * 8;                // 0..504
        s16x8 v = *(const s16x8*)(ybf + (size_t)(row0 + r) * DIM + k0);
        int tile = (k0 >> 5) * 2 + (r >> 4);
        int off  = tile * 512 + ((k0 >> 3) & 3) * 128 + (r & 15) * 8;
        *(s16x8*)&ys[off] = v;
    }

    float bv1[8], bv2[4];
#pragma unroll
    for (int cg = 0; cg < 8; ++cg) bv1[cg] = b1[w * 128 + cg * 16 + lc];
#pragma unroll
    for (int cf = 0; cf < 4; ++cf) bv2[cf] = b2[w * 64 + cf * 16 + lc];

    const u16* p1 = W1P + ((size_t)w << 16) + lane * 8;   // + (ks*8+cg)*512
    const u16* p2 = W2P + ((size_t)w << 16) + lane * 8;   // + (ks*4+cf)*512

    __syncthreads();

    // ========== phase 1: h = tanh(y @ W1 + b1) -> hs  (wave: 32r x 128c, K=512) ==========
    {
        f32x4 acc1[2][8];
#pragma unroll
        for (int m = 0; m < 2; ++m)
#pragma unroll
            for (int cg = 0; cg < 8; ++cg)
                acc1[m][cg] = (f32x4){0.f, 0.f, 0.f, 0.f};

        s16x8 bA[8], bB[8];
#pragma unroll
        for (int cg = 0; cg < 8; ++cg)
            bA[cg] = *(const s16x8*)(p1 + cg * 512);

#pragma unroll
        for (int ks = 0; ks < 16; ++ks) {
            s16x8* bc = (ks & 1) ? bB : bA;
            s16x8* bn = (ks & 1) ? bA : bB;
            if (ks < 15) {
#pragma unroll
                for (int cg = 0; cg < 8; ++cg)
                    bn[cg] = *(const s16x8*)(p1 + ((ks + 1) * 8 + cg) * 512);
            }
            s16x8 a0 = *(const s16x8*)&ys[(ks * 2 + 0) * 512 + q * 128 + lc * 8];
            s16x8 a1 = *(const s16x8*)&ys[(ks * 2 + 1) * 512 + q * 128 + lc * 8];
#pragma unroll
            for (int cg = 0; cg < 8; ++cg) {
                acc1[0][cg] = __builtin_amdgcn_mfma_f32_16x16x32_bf16(a0, bc[cg], acc1[0][cg], 0, 0, 0);
                acc1[1][cg] = __builtin_amdgcn_mfma_f32_16x16x32_bf16(a1, bc[cg], acc1[1][cg], 0, 0, 0);
            }
        }

#pragma unroll
        for (int m = 0; m < 2; ++m)
#pragma unroll
            for (int cg = 0; cg < 8; ++cg) {
                int tile = (w * 4 + (cg >> 1)) * 2 + m;
                int base = tile * 512 + ((cg & 1) * 2 + (lc >> 3)) * 128 + (lc & 7);
#pragma unroll
                for (int j = 0; j < 4; ++j)
                    hs[base + (lr + j) * 8] = f2bf(fast_tanh(acc1[m][cg][j] + bv1[cg]));
            }
    }
    __syncthreads();

    // ========== phase 2: k = h @ W2 + b2 ; RK4 epilogue  (wave: 32r x 64c, K=1024) ==========
    {
        f32x4 acc2[2][4];
#pragma unroll
        for (int m = 0; m < 2; ++m)
#pragma unroll
            for (int cf = 0; cf < 4; ++cf)
                acc2[m][cf] = (f32x4){0.f, 0.f, 0.f, 0.f};

        s16x8 cA[4], cB[4];
#pragma unroll
        for (int cf = 0; cf < 4; ++cf)
            cA[cf] = *(const s16x8*)(p2 + cf * 512);

#pragma unroll
        for (int ks = 0; ks < 32; ++ks) {
            s16x8* bc = (ks & 1) ? cB : cA;
            s16x8* bn = (ks & 1) ? cA : cB;
            if (ks < 31) {
#pragma unroll
                for (int cf = 0; cf < 4; ++cf)
                    bn[cf] = *(const s16x8*)(p2 + ((ks + 1) * 4 + cf) * 512);
            }
            s16x8 a0 = *(const s16x8*)&hs[(ks * 2 + 0) * 512 + q * 128 + lc * 8];
            s16x8 a1 = *(const s16x8*)&hs[(ks * 2 + 1) * 512 + q * 128 + lc * 8];
#pragma unroll
            for (int cf = 0; cf < 4; ++cf) {
                acc2[0][cf] = __builtin_amdgcn_mfma_f32_16x16x32_bf16(a0, bc[cf], acc2[0][cf], 0, 0, 0);
                acc2[1][cf] = __builtin_amdgcn_mfma_f32_16x16x32_bf16(a1, bc[cf], acc2[1][cf], 0, 0, 0);
            }
        }

        const float dtv = tgrid[step + 1] - tgrid[step];
#pragma unroll
        for (int m = 0; m < 2; ++m)
#pragma unroll
            for (int cf = 0; cf < 4; ++cf) {
#pragma unroll
                for (int j = 0; j < 4; ++j) {
                    int row = row0 + m * 16 + lr + j;
                    int col = w * 64 + cf * 16 + lc;
                    size_t idx = (size_t)row * DIM + col;
                    float v = acc2[m][cf][j] + bv2[cf];
                    float yb = ybase_g[idx];
                    if (st == 0) {
                        accum[idx] = v;
                        ybf_next[idx] = f2bf(yb + 0.5f * dtv * v);
                    } else if (st == 1) {
                        accum[idx] += 2.0f * v;
                        ybf_next[idx] = f2bf(yb + 0.5f * dtv * v);
                    } else if (st == 2) {
                        accum[idx] += 2.0f * v;
                        ybf_next[idx] = f2bf(yb + dtv * v);
                    } else {
                        float y1 = yb + (dtv * (1.0f / 6.0f)) * (accum[idx] + v);
                        ynext_g[idx] = y1;
                        ybf_next[idx] = f2bf(y1);
                    }
                }
            }
    }
}

extern "C" void kernel_launch(void* const* d_in, const int* in_sizes, int n_in,
                              void* d_out, int out_size, void* d_ws, size_t ws_size,
                              hipStream_t stream) {
    (void)in_sizes; (void)n_in; (void)out_size; (void)ws_size;
    const float* x0 = (const float*)d_in[0];
    const float* t  = (const float*)d_in[1];
    const float* W1 = (const float*)d_in[2];
    const float* b1 = (const float*)d_in[3];
    const float* W2 = (const float*)d_in[4];
    const float* b2 = (const float*)d_in[5];
    float* out = (float*)d_out;

    char* ws = (char*)d_ws;
    u16*   ybf   = (u16*)  (ws);               //  4 MB [4096,512] bf16 y-arg
    float* accum = (float*)(ws + (4u  << 20)); //  8 MB [4096,512] f32
    u16*   W1P   = (u16*)  (ws + (12u << 20)); //  1 MB packed
    u16*   W2P   = (u16*)  (ws + (13u << 20)); //  1 MB packed

    init_state<<<(BATCH * DIM + 255) / 256, 256, 0, stream>>>(x0, out, ybf, BATCH * DIM);
    pack_w1<<<(HID * DIM) / 256, 256, 0, stream>>>(W1, W1P);
    pack_w2<<<(DIM * HID) / 256, 256, 0, stream>>>(W2, W2P);

    for (int s = 0; s < TSTEPS - 1; ++s) {
        const float* yb_s = out + (size_t)s * BATCH * DIM;
        float*       yn_s = out + (size_t)(s + 1) * BATCH * DIM;
        for (int st = 0; st < 4; ++st) {
            ode_stage<<<NBLK, NTHR, 0, stream>>>(ybf, b1, b2, W1P, W2P,
                                                 yb_s, yn_s, accum, ybf, t, s, st);
        }
    }
}

// Round 16
// 2998.243 us; speedup vs baseline: 1.2612x; 1.2612x over previous
//
// R16: fused RK4 stage, weights staged coalesced via global_load_lds into
// per-wave PRIVATE LDS buffers (zero barriers in K-loops), counted vmcnt.
#include <hip/hip_runtime.h>
#include <hip/hip_bf16.h>
#include <cstdint>

#define BATCH 4096
#define DIM   512
#define HID   1024
#define TSTEPS 20
#define NBLK  128
#define NTHR  512

typedef unsigned short u16;
typedef short s16x8 __attribute__((ext_vector_type(8)));
typedef float f32x4 __attribute__((ext_vector_type(4)));

__device__ __forceinline__ u16 f2bf(float f) {
    unsigned int u = __float_as_uint(f);
    u = (u + 0x7FFFu + ((u >> 16) & 1u)) >> 16;   // RNE
    return (u16)u;
}

__device__ __forceinline__ float fast_tanh(float x) {
    float ax = __builtin_fabsf(x);
    float e  = __expf(2.0f * ax);
    float t  = 1.0f - 2.0f * __builtin_amdgcn_rcpf(e + 1.0f);
    return __builtin_copysignf(t, x);
}

__global__ void init_state(const float* __restrict__ x0, float* __restrict__ out0,
                           u16* __restrict__ ybf, int n) {
    int i = blockIdx.x * blockDim.x + threadIdx.x;
    if (i < n) { float v = x0[i]; out0[i] = v; ybf[i] = f2bf(v); }
}

// Pack W1 [512k][1024n] f32 -> W1P bf16, B-frag order:
// u16 idx = (((w*16 + ks)*8 + cg)*64 + lane)*8 + e
__global__ void pack_w1(const float* __restrict__ W1, u16* __restrict__ W1P) {
    int pid = blockIdx.x * 256 + threadIdx.x;
    int e  = pid & 7;
    int l  = (pid >> 3) & 63;
    int cg = (pid >> 9) & 7;
    int ks = (pid >> 12) & 15;
    int w  = (pid >> 16) & 7;
    int n = w * 128 + cg * 16 + (l & 15);
    int k = ks * 32 + (l >> 4) * 8 + e;
    W1P[pid] = f2bf(W1[(size_t)k * HID + n]);
}

// Pack W2 [1024k][512n] f32 -> W2P bf16:
// u16 idx = (((w*32 + ks)*4 + cf)*64 + lane)*8 + e
__global__ void pack_w2(const float* __restrict__ W2, u16* __restrict__ W2P) {
    int pid = blockIdx.x * 256 + threadIdx.x;
    int e  = pid & 7;
    int l  = (pid >> 3) & 63;
    int cf = (pid >> 9) & 3;
    int ks = (pid >> 11) & 31;
    int w  = (pid >> 16) & 7;
    int n = w * 64 + cf * 16 + (l & 15);
    int k = ks * 32 + (l >> 4) * 8 + e;
    W2P[pid] = f2bf(W2[(size_t)k * DIM + n]);
}

// LDS map (u16 units), 144 KiB total:
//   phase1: ys [0,16384) | wb1 [16384,40960) (8 waves x 3 bufs x 1024) | hs [40960,73728)
//   phase2: wb2 [0,32768) (8 waves x 4 bufs x 1024; ys+wb1 dead)       | hs persists
__global__ __launch_bounds__(NTHR, 1) void ode_stage(
    const u16* __restrict__ ybf,
    const float* __restrict__ b1, const float* __restrict__ b2,
    const u16* __restrict__ W1P, const u16* __restrict__ W2P,
    const float* __restrict__ ybase_g,
    float* __restrict__ ynext_g,
    float* __restrict__ accum,
    u16* __restrict__ ybf_next,
    const float* __restrict__ tgrid, int step, int st)
{
    __shared__ u16 lds[73728];
    u16* ys  = lds;
    u16* wb1 = lds + 16384;
    u16* hs  = lds + 40960;
    u16* wb2 = lds;

    const int tid  = threadIdx.x;
    const int lane = tid & 63;
    const int w    = tid >> 6;
    const int row0 = blockIdx.x * 32;
    const int lr   = (lane >> 4) * 4;
    const int lc   = lane & 15;
    const int q    = lane >> 4;

    // ---- y strip -> ys frag-tiles (coalesced; R14-proven layout) ----
#pragma unroll
    for (int t_ = 0; t_ < 4; ++t_) {
        int c  = tid + t_ * NTHR;
        int r  = c >> 6;
        int k0 = (c & 63) * 8;
        s16x8 v = *(const s16x8*)(ybf + (size_t)(row0 + r) * DIM + k0);
        int tile = (k0 >> 5) * 2 + (r >> 4);
        int off  = tile * 512 + ((k0 >> 3) & 3) * 128 + (r & 15) * 8;
        *(s16x8*)&ys[off] = v;
    }

    float bv1[8], bv2[4];
#pragma unroll
    for (int cg = 0; cg < 8; ++cg) bv1[cg] = b1[w * 128 + cg * 16 + lc];
#pragma unroll
    for (int cf = 0; cf < 4; ++cf) bv2[cf] = b2[w * 64 + cf * 16 + lc];
    float dtv = tgrid[step + 1] - tgrid[step];

    // drain all prior VMEM so counted vmcnt below sees only stage loads
    asm volatile("s_waitcnt vmcnt(0)" ::: "memory");
#pragma unroll
    for (int i = 0; i < 8; ++i) asm volatile("" : "+v"(bv1[i]));
#pragma unroll
    for (int i = 0; i < 4; ++i) asm volatile("" : "+v"(bv2[i]));
    asm volatile("" : "+v"(dtv));

    __syncthreads();

    // ================= phase 1: h = tanh(y @ W1 + b1) -> hs =================
    // 4 passes, wave w covers cols [w*128 + p*32, +32) per pass; K=512 (16 ks)
#pragma clang loop unroll(disable)
    for (int p = 0; p < 4; ++p) {
        f32x4 acc[2][2];
#pragma unroll
        for (int m = 0; m < 2; ++m)
#pragma unroll
            for (int t = 0; t < 2; ++t)
                acc[m][t] = (f32x4){0.f, 0.f, 0.f, 0.f};

        // prologue: stage ks=0,1 into bufs 0,1 (2 loads each)
#pragma unroll
        for (int b = 0; b < 2; ++b)
#pragma unroll
            for (int t = 0; t < 2; ++t) {
                const u16* src = W1P + (size_t)((w * 16 + b) * 8 + p * 2 + t) * 512 + lane * 8;
                __builtin_amdgcn_global_load_lds(
                    (const __attribute__((address_space(1))) unsigned int*)src,
                    (__attribute__((address_space(3))) unsigned int*)&wb1[(w * 3 + b) * 1024 + t * 512],
                    16, 0, 0);
            }

#pragma unroll
        for (int ks = 0; ks < 16; ++ks) {
            if (ks < 15) asm volatile("s_waitcnt vmcnt(2)" ::: "memory");
            else         asm volatile("s_waitcnt vmcnt(0)" ::: "memory");

            const u16* wbuf = &wb1[(w * 3 + ks % 3) * 1024];
            s16x8 bf0 = *(const s16x8*)&wbuf[lane * 8];
            s16x8 bf1 = *(const s16x8*)&wbuf[512 + lane * 8];
            s16x8 a0 = *(const s16x8*)&ys[(ks * 2 + 0) * 512 + q * 128 + lc * 8];
            s16x8 a1 = *(const s16x8*)&ys[(ks * 2 + 1) * 512 + q * 128 + lc * 8];

            if (ks + 2 < 16) {
                // WAR guard: older ds_reads (iter ks-1, same buffer) must be retired
                asm volatile("s_waitcnt lgkmcnt(4)" ::: "memory");
                int b = (ks + 2) % 3;
#pragma unroll
                for (int t = 0; t < 2; ++t) {
                    const u16* src = W1P + (size_t)((w * 16 + ks + 2) * 8 + p * 2 + t) * 512 + lane * 8;
                    __builtin_amdgcn_global_load_lds(
                        (const __attribute__((address_space(1))) unsigned int*)src,
                        (__attribute__((address_space(3))) unsigned int*)&wb1[(w * 3 + b) * 1024 + t * 512],
                        16, 0, 0);
                }
            }

            acc[0][0] = __builtin_amdgcn_mfma_f32_16x16x32_bf16(a0, bf0, acc[0][0], 0, 0, 0);
            acc[0][1] = __builtin_amdgcn_mfma_f32_16x16x32_bf16(a0, bf1, acc[0][1], 0, 0, 0);
            acc[1][0] = __builtin_amdgcn_mfma_f32_16x16x32_bf16(a1, bf0, acc[1][0], 0, 0, 0);
            acc[1][1] = __builtin_amdgcn_mfma_f32_16x16x32_bf16(a1, bf1, acc[1][1], 0, 0, 0);
        }

        // pass epilogue: tanh -> hs frag-tiles (R14-proven formula, cg = 2p+t)
#pragma unroll
        for (int m = 0; m < 2; ++m)
#pragma unroll
            for (int t = 0; t < 2; ++t) {
                int cg = p * 2 + t;
                int tile = (w * 4 + p) * 2 + m;
                int base = tile * 512 + (t * 2 + (lc >> 3)) * 128 + (lc & 7);
#pragma unroll
                for (int j = 0; j < 4; ++j)
                    hs[base + (lr + j) * 8] = f2bf(fast_tanh(acc[m][t][j] + bv1[cg]));
            }
    }

    __syncthreads();   // hs complete; ys/wb1 regions die, wb2 takes over

    // ================= phase 2: k = h @ W2 + b2 ; RK4 epilogue =================
    // 2 passes, wave w covers cols [w*64 + p2*32, +32); K=1024 (32 ks), depth-3
#pragma clang loop unroll(disable)
    for (int p2 = 0; p2 < 2; ++p2) {
        f32x4 acc[2][2];
#pragma unroll
        for (int m = 0; m < 2; ++m)
#pragma unroll
            for (int t = 0; t < 2; ++t)
                acc[m][t] = (f32x4){0.f, 0.f, 0.f, 0.f};

        // prologue: stage ks=0,1,2 into bufs 0,1,2
#pragma unroll
        for (int b = 0; b < 3; ++b)
#pragma unroll
            for (int t = 0; t < 2; ++t) {
                const u16* src = W2P + (size_t)((w * 32 + b) * 4 + p2 * 2 + t) * 512 + lane * 8;
                __builtin_amdgcn_global_load_lds(
                    (const __attribute__((address_space(1))) unsigned int*)src,
                    (__attribute__((address_space(3))) unsigned int*)&wb2[(w * 4 + b) * 1024 + t * 512],
                    16, 0, 0);
            }

#pragma unroll
        for (int ks = 0; ks < 32; ++ks) {
            if (ks < 30)      asm volatile("s_waitcnt vmcnt(4)" ::: "memory");
            else if (ks == 30) asm volatile("s_waitcnt vmcnt(2)" ::: "memory");
            else              asm volatile("s_waitcnt vmcnt(0)" ::: "memory");

            const u16* wbuf = &wb2[(w * 4 + ks % 4) * 1024];
            s16x8 bf0 = *(const s16x8*)&wbuf[lane * 8];
            s16x8 bf1 = *(const s16x8*)&wbuf[512 + lane * 8];
            s16x8 a0 = *(const s16x8*)&hs[(ks * 2 + 0) * 512 + q * 128 + lc * 8];
            s16x8 a1 = *(const s16x8*)&hs[(ks * 2 + 1) * 512 + q * 128 + lc * 8];

            if (ks + 3 < 32) {
                asm volatile("s_waitcnt lgkmcnt(4)" ::: "memory");
                int b = (ks + 3) % 4;
#pragma unroll
                for (int t = 0; t < 2; ++t) {
                    const u16* src = W2P + (size_t)((w * 32 + ks + 3) * 4 + p2 * 2 + t) * 512 + lane * 8;
                    __builtin_amdgcn_global_load_lds(
                        (const __attribute__((address_space(1))) unsigned int*)src,
                        (__attribute__((address_space(3))) unsigned int*)&wb2[(w * 4 + b) * 1024 + t * 512],
                        16, 0, 0);
                }
            }

            acc[0][0] = __builtin_amdgcn_mfma_f32_16x16x32_bf16(a0, bf0, acc[0][0], 0, 0, 0);
            acc[0][1] = __builtin_amdgcn_mfma_f32_16x16x32_bf16(a0, bf1, acc[0][1], 0, 0, 0);
            acc[1][0] = __builtin_amdgcn_mfma_f32_16x16x32_bf16(a1, bf0, acc[1][0], 0, 0, 0);
            acc[1][1] = __builtin_amdgcn_mfma_f32_16x16x32_bf16(a1, bf1, acc[1][1], 0, 0, 0);
        }

        // pass epilogue: RK4 (cf = 2*p2 + t), state in global (R14-proven)
#pragma unroll
        for (int m = 0; m < 2; ++m)
#pragma unroll
            for (int t = 0; t < 2; ++t) {
                int cf = p2 * 2 + t;
#pragma unroll
                for (int j = 0; j < 4; ++j) {
                    int row = row0 + m * 16 + lr + j;
                    int col = w * 64 + cf * 16 + lc;
                    size_t idx = (size_t)row * DIM + col;
                    float v = acc[m][t][j] + bv2[cf];
                    float yb = ybase_g[idx];
                    if (st == 0) {
                        accum[idx] = v;
                        ybf_next[idx] = f2bf(yb + 0.5f * dtv * v);
                    } else if (st == 1) {
                        accum[idx] += 2.0f * v;
                        ybf_next[idx] = f2bf(yb + 0.5f * dtv * v);
                    } else if (st == 2) {
                        accum[idx] += 2.0f * v;
                        ybf_next[idx] = f2bf(yb + dtv * v);
                    } else {
                        float y1 = yb + (dtv * (1.0f / 6.0f)) * (accum[idx] + v);
                        ynext_g[idx] = y1;
                        ybf_next[idx] = f2bf(y1);
                    }
                }
            }
    }
}

extern "C" void kernel_launch(void* const* d_in, const int* in_sizes, int n_in,
                              void* d_out, int out_size, void* d_ws, size_t ws_size,
                              hipStream_t stream) {
    (void)in_sizes; (void)n_in; (void)out_size; (void)ws_size;
    const float* x0 = (const float*)d_in[0];
    const float* t  = (const float*)d_in[1];
    const float* W1 = (const float*)d_in[2];
    const float* b1 = (const float*)d_in[3];
    const float* W2 = (const float*)d_in[4];
    const float* b2 = (const float*)d_in[5];
    float* out = (float*)d_out;

    char* ws = (char*)d_ws;
    u16*   ybf   = (u16*)  (ws);               //  4 MB [4096,512] bf16 y-arg
    float* accum = (float*)(ws + (4u  << 20)); //  8 MB [4096,512] f32
    u16*   W1P   = (u16*)  (ws + (12u << 20)); //  1 MB packed
    u16*   W2P   = (u16*)  (ws + (13u << 20)); //  1 MB packed

    init_state<<<(BATCH * DIM + 255) / 256, 256, 0, stream>>>(x0, out, ybf, BATCH * DIM);
    pack_w1<<<(HID * DIM) / 256, 256, 0, stream>>>(W1, W1P);
    pack_w2<<<(DIM * HID) / 256, 256, 0, stream>>>(W2, W2P);

    for (int s = 0; s < TSTEPS - 1; ++s) {
        const float* yb_s = out + (size_t)s * BATCH * DIM;
        float*       yn_s = out + (size_t)(s + 1) * BATCH * DIM;
        for (int st = 0; st < 4; ++st) {
            ode_stage<<<NBLK, NTHR, 0, stream>>>(ybf, b1, b2, W1P, W2P,
                                                 yb_s, yn_s, accum, ybf, t, s, st);
        }
    }
}

// Round 17
// 1754.672 us; speedup vs baseline: 2.1550x; 1.7087x over previous
//
// R17 = R11 + one-barrier K-loop (3/4-buf) + GEMM2 depth-3 + fast_tanh epilogue
#include <hip/hip_runtime.h>
#include <hip/hip_bf16.h>
#include <cstdint>

#define BATCH 4096
#define DIM   512
#define HID   1024
#define TSTEPS 20

typedef unsigned short u16;
typedef short s16x8 __attribute__((ext_vector_type(8)));
typedef float f32x4 __attribute__((ext_vector_type(4)));

__device__ __forceinline__ u16 f2bf(float f) {
    unsigned int u = __float_as_uint(f);
    u = (u + 0x7FFFu + ((u >> 16) & 1u)) >> 16;   // RNE
    return (u16)u;
}

__device__ __forceinline__ float fast_tanh(float x) {
    float ax = __builtin_fabsf(x);
    float e  = __expf(2.0f * ax);                 // inf for large ax -> t = 1
    float t  = 1.0f - 2.0f * __builtin_amdgcn_rcpf(e + 1.0f);
    return __builtin_copysignf(t, x);
}

// out[0] = x0 ; ybf = bf16(x0)
__global__ void init_state(const float* __restrict__ x0, float* __restrict__ out0,
                           u16* __restrict__ ybf, int n) {
    int i = blockIdx.x * blockDim.x + threadIdx.x;
    if (i < n) { float v = x0[i]; out0[i] = v; ybf[i] = f2bf(v); }
}

// Wt[n*K + k] = bf16(W[k*N + n])   (W is [K][N] row-major)
__global__ void transpose_convert(const float* __restrict__ W, u16* __restrict__ Wt,
                                  int K, int N) {
    int n = blockIdx.x * 32 + threadIdx.x;
    int k = blockIdx.y * 8  + threadIdx.y;
    if (n < N && k < K) Wt[(size_t)n * K + k] = f2bf(W[(size_t)k * N + n]);
}

// C = A[M,K] * Bt[N,K]^T, fused epilogue. (DEPTH+1)-buffer depth-DEPTH pipelined
// K-loop, counted vmcnt, ONE barrier per iteration (WAR covered by next top barrier).
// EPI==0 : act = bf16(fast_tanh(C + bias))      (GEMM1)
// EPI==1..4 : RK4 stage epilogues               (GEMM2, N == DIM)
template<int BM, int BN, int EPI, int DEPTH>
__global__ __launch_bounds__(256, 2) void gemm_bt(
    const u16* __restrict__ A,
    const u16* __restrict__ Bt,
    const float* __restrict__ bias,
    int M, int N, int K,
    u16* __restrict__ actOut,
    const float* __restrict__ ybase,
    float* __restrict__ ynext,
    float* __restrict__ accum,
    u16* __restrict__ ybf,
    const float* __restrict__ tgrid, int step)
{
    constexpr int AC = BM / 8;          // A chunks (1 KiB each) per K-tile
    constexpr int BC = BN / 8;
    constexpr int CPW = (AC + BC) / 4;  // global_load_lds per thread per tile
    constexpr int NBUF = DEPTH + 1;
    static_assert((DEPTH == 2 && CPW == 6) || (DEPTH == 3 && CPW == 4),
                  "vmcnt literals below assume these configs");
    constexpr int WM = BM / 32;
    constexpr int WN = BN / 32;
    constexpr int BUFE = (BM + BN) * 64;   // u16 elems per LDS buffer

    __shared__ u16 lds[NBUF * BUFE];

    const int tid  = threadIdx.x;
    const int lane = tid & 63;
    const int wid  = tid >> 6;
    const int wy   = wid >> 1;
    const int wx   = wid & 1;
    const int brow = blockIdx.x * BM;
    const int bcol = blockIdx.y * BN;

    const int srow = lane >> 3;                    // row within 8-row group
    const int scol = ((lane & 7) ^ srow) * 8;      // pre-swizzled k offset (elems)

    f32x4 acc[WM][WN];
#pragma unroll
    for (int m = 0; m < WM; ++m)
#pragma unroll
        for (int n = 0; n < WN; ++n)
            acc[m][n] = (f32x4){0.f, 0.f, 0.f, 0.f};

    auto stage = [&](int buf, int kt) {
        const int k0 = kt * 64;
        u16* base = &lds[buf * BUFE];
#pragma unroll
        for (int c0 = 0; c0 < CPW; ++c0) {
            int c = wid * CPW + c0;            // wave-uniform
            if (c < AC) {
                int row = c * 8 + srow;
                const u16* g = A + (size_t)(brow + row) * K + k0 + scol;
                __builtin_amdgcn_global_load_lds(
                    (const __attribute__((address_space(1))) unsigned int*)g,
                    (__attribute__((address_space(3))) unsigned int*)&base[c * 512],
                    16, 0, 0);
            } else {
                int cb = c - AC;
                int row = cb * 8 + srow;
                const u16* g = Bt + (size_t)(bcol + row) * K + k0 + scol;
                __builtin_amdgcn_global_load_lds(
                    (const __attribute__((address_space(1))) unsigned int*)g,
                    (__attribute__((address_space(3))) unsigned int*)&base[BM * 64 + cb * 512],
                    16, 0, 0);
            }
        }
    };

    const int NT = K / 64;

    // prologue: DEPTH tiles in flight
#pragma unroll
    for (int d = 0; d < DEPTH; ++d) stage(d, d);

    for (int kt = 0; kt < NT; ++kt) {
        // wait until tile kt's loads complete; keep later tiles in flight
        if constexpr (DEPTH == 2) {
            if (kt < NT - 1) asm volatile("s_waitcnt vmcnt(6)" ::: "memory");
            else             asm volatile("s_waitcnt vmcnt(0)" ::: "memory");
        } else {
            if (kt < NT - 2)       asm volatile("s_waitcnt vmcnt(8)" ::: "memory");
            else if (kt == NT - 2) asm volatile("s_waitcnt vmcnt(4)" ::: "memory");
            else                   asm volatile("s_waitcnt vmcnt(0)" ::: "memory");
        }
        // single barrier: all waves' tile-kt loads landed; also seals WAR for the
        // buffer staged below (last read by all waves in iter kt-1).
        __builtin_amdgcn_s_barrier();

        const char* lb = (const char*)&lds[(kt % NBUF) * BUFE];

        s16x8 af[2][WM], bfr[2][WN];
#pragma unroll
        for (int ks = 0; ks < 2; ++ks) {
#pragma unroll
            for (int m = 0; m < WM; ++m) {
                int row = wy * (BM / 2) + m * 16 + (lane & 15);
                unsigned byte = (unsigned)(row * 128 + (ks * 32 + (lane >> 4) * 8) * 2);
                byte ^= (unsigned)((row & 7) << 4);
                af[ks][m] = *(const s16x8*)(lb + byte);
            }
#pragma unroll
            for (int n = 0; n < WN; ++n) {
                int row = wx * (BN / 2) + n * 16 + (lane & 15);
                unsigned byte = (unsigned)(BM * 128 + row * 128 + (ks * 32 + (lane >> 4) * 8) * 2);
                byte ^= (unsigned)((row & 7) << 4);
                bfr[ks][n] = *(const s16x8*)(lb + byte);
            }
        }

        // issue tile kt+DEPTH while tile kt computes
        if (kt + DEPTH < NT) stage((kt + DEPTH) % NBUF, kt + DEPTH);

#pragma unroll
        for (int ks = 0; ks < 2; ++ks)
#pragma unroll
            for (int m = 0; m < WM; ++m)
#pragma unroll
                for (int n = 0; n < WN; ++n)
                    acc[m][n] = __builtin_amdgcn_mfma_f32_16x16x32_bf16(
                        af[ks][m], bfr[ks][n], acc[m][n], 0, 0, 0);
    }

    // ---- epilogue ----
    float dtv = 0.f;
    if constexpr (EPI >= 1) dtv = tgrid[step + 1] - tgrid[step];

#pragma unroll
    for (int m = 0; m < WM; ++m) {
        int row0 = brow + wy * (BM / 2) + m * 16 + (lane >> 4) * 4;
#pragma unroll
        for (int n = 0; n < WN; ++n) {
            int col = bcol + wx * (BN / 2) + n * 16 + (lane & 15);
            float bv = bias[col];
#pragma unroll
            for (int j = 0; j < 4; ++j) {
                int row = row0 + j;
                float v = acc[m][n][j] + bv;
                if constexpr (EPI == 0) {
                    actOut[(size_t)row * HID + col] = f2bf(fast_tanh(v));
                } else {
                    size_t idx = (size_t)row * DIM + col;
                    float yb = ybase[idx];
                    if constexpr (EPI == 1) {
                        accum[idx] = v;
                        ybf[idx] = f2bf(yb + 0.5f * dtv * v);
                    } else if constexpr (EPI == 2) {
                        accum[idx] += 2.0f * v;
                        ybf[idx] = f2bf(yb + 0.5f * dtv * v);
                    } else if constexpr (EPI == 3) {
                        accum[idx] += 2.0f * v;
                        ybf[idx] = f2bf(yb + dtv * v);
                    } else {  // EPI == 4
                        float yn = yb + (dtv * (1.0f / 6.0f)) * (accum[idx] + v);
                        ynext[idx] = yn;
                        ybf[idx] = f2bf(yn);
                    }
                }
            }
        }
    }
}

extern "C" void kernel_launch(void* const* d_in, const int* in_sizes, int n_in,
                              void* d_out, int out_size, void* d_ws, size_t ws_size,
                              hipStream_t stream) {
    (void)in_sizes; (void)n_in; (void)out_size; (void)ws_size;
    const float* x0 = (const float*)d_in[0];
    const float* t  = (const float*)d_in[1];
    const float* W1 = (const float*)d_in[2];
    const float* b1 = (const float*)d_in[3];
    const float* W2 = (const float*)d_in[4];
    const float* b2 = (const float*)d_in[5];
    float* out = (float*)d_out;

    char* ws = (char*)d_ws;
    u16*   ybf   = (u16*)  (ws);               //  4 MB  [4096,512]  bf16
    u16*   act   = (u16*)  (ws + (4u  << 20)); //  8 MB  [4096,1024] bf16
    float* accum = (float*)(ws + (12u << 20)); //  8 MB  [4096,512]  f32
    u16*   W1T   = (u16*)  (ws + (20u << 20)); //  1 MB  [1024,512]  bf16
    u16*   W2T   = (u16*)  (ws + (21u << 20)); //  1 MB  [512,1024]  bf16

    init_state<<<(BATCH * DIM + 255) / 256, 256, 0, stream>>>(x0, out, ybf, BATCH * DIM);
    transpose_convert<<<dim3(HID / 32, DIM / 8), dim3(32, 8), 0, stream>>>(W1, W1T, DIM, HID);
    transpose_convert<<<dim3(DIM / 32, HID / 8), dim3(32, 8), 0, stream>>>(W2, W2T, HID, DIM);

    dim3 blk(256);
    dim3 g1(BATCH / 128, HID / 64);    // 32 x 16 = 512 blocks (2 per CU)
    dim3 g2(BATCH / 64,  DIM / 64);    // 64 x 8  = 512 blocks (2 per CU)

    for (int s = 0; s < TSTEPS - 1; ++s) {
        const float* yb_s = out + (size_t)s * BATCH * DIM;
        float*       yn_s = out + (size_t)(s + 1) * BATCH * DIM;

        // stage 1: k1 = f(y)
        gemm_bt<128,64,0,2><<<g1, blk, 0, stream>>>(ybf, W1T, b1, BATCH, HID, DIM,
                                                    act, nullptr, nullptr, nullptr, nullptr, nullptr, 0);
        gemm_bt<64,64,1,3><<<g2, blk, 0, stream>>>(act, W2T, b2, BATCH, DIM, HID,
                                                   nullptr, yb_s, yn_s, accum, ybf, t, s);
        // stage 2: k2 = f(y + dt/2 * k1)
        gemm_bt<128,64,0,2><<<g1, blk, 0, stream>>>(ybf, W1T, b1, BATCH, HID, DIM,
                                                    act, nullptr, nullptr, nullptr, nullptr, nullptr, 0);
        gemm_bt<64,64,2,3><<<g2, blk, 0, stream>>>(act, W2T, b2, BATCH, DIM, HID,
                                                   nullptr, yb_s, yn_s, accum, ybf, t, s);
        // stage 3: k3 = f(y + dt/2 * k2)
        gemm_bt<128,64,0,2><<<g1, blk, 0, stream>>>(ybf, W1T, b1, BATCH, HID, DIM,
                                                    act, nullptr, nullptr, nullptr, nullptr, nullptr, 0);
        gemm_bt<64,64,3,3><<<g2, blk, 0, stream>>>(act, W2T, b2, BATCH, DIM, HID,
                                                   nullptr, yb_s, yn_s, accum, ybf, t, s);
        // stage 4: y' = y + dt/6 * (k1 + 2k2 + 2k3 + k4)
        gemm_bt<128,64,0,2><<<g1, blk, 0, stream>>>(ybf, W1T, b1, BATCH, HID, DIM,
                                                    act, nullptr, nullptr, nullptr, nullptr, nullptr, 0);
        gemm_bt<64,64,4,3><<<g2, blk, 0, stream>>>(act, W2T, b2, BATCH, DIM, HID,
                                                   nullptr, yb_s, yn_s, accum, ybf, t, s);
    }
}